// Round 12
// baseline (1922.707 us; speedup 1.0000x reference)
//
#include <hip/hip_runtime.h>

#define NT 512
#define ND 256
#define NH 1024
#define NB 64
// R12: geometry change on the R11 protocol — 128 wgs = 4 bgs x 32 slices(32 rows),
// 512 threads (8 waves, 2/SIMD). Wave w owns K-slice [w*128,+128).
// Halves the per-step LLC broadcast (4 MB vs 8) and sync fan-in (32 vs 64),
// and gives each CU 2 waves/SIMD of latency hiding. Handoff protocol, flags,
// deferred outputs identical to R11 (proven).

typedef float f32x4 __attribute__((ext_vector_type(4)));
typedef short bf16x8 __attribute__((ext_vector_type(8)));

__device__ __forceinline__ unsigned short f2bf(float f) {     // RNE
  unsigned u = __builtin_bit_cast(unsigned, f);
  u += 0x7fffu + ((u >> 16) & 1u);
  return (unsigned short)(u >> 16);
}
__device__ __forceinline__ float bflo(unsigned u) {
  return __builtin_bit_cast(float, u << 16);
}
__device__ __forceinline__ float bfhi(unsigned u) {
  return __builtin_bit_cast(float, u & 0xffff0000u);
}
__device__ __forceinline__ bf16x8 pack8(float4 a, float4 b) {
  bf16x8 r;
  r[0] = (short)f2bf(a.x); r[1] = (short)f2bf(a.y);
  r[2] = (short)f2bf(a.z); r[3] = (short)f2bf(a.w);
  r[4] = (short)f2bf(b.x); r[5] = (short)f2bf(b.y);
  r[6] = (short)f2bf(b.z); r[7] = (short)f2bf(b.w);
  return r;
}

__global__ void __launch_bounds__(512, 1)
rnn_step_kernel(const float* __restrict__ x,
                const float* __restrict__ Wx_w,
                const float* __restrict__ Wx_b,
                const float* __restrict__ Wh_w,
                const float* __restrict__ Ws_w,
                const float* __restrict__ Ws_b,
                const float* __restrict__ Us_w,
                float* __restrict__ out,
                unsigned short* __restrict__ hbuf,   // bf16 [2][NB][NH]
                unsigned int* __restrict__ flags)    // [4][NT][32]
{
  const int tid = (int)threadIdx.x;
  const int w   = tid >> 6;        // wave 0..7
  const int l   = tid & 63;        // lane
  const int bm  = l & 15;          // mfma row/col index for A/B frags
  const int lg  = l >> 4;          // lane group
  const int sl  = (int)blockIdx.x & 31;   // 32 slices of 32 rows
  const int bg  = (int)blockIdx.x >> 5;   // 4 batch groups of 16
  const int r_base = sl * 32;
  const int b_base = bg * 16;
  const int ro = tid & 31;         // epilogue row (consecutive lanes -> rows)
  const int bo = tid >> 5;         // epilogue batch 0..15
  const int rg = r_base + ro;
  const int b_glob = b_base + bo;

  __shared__ unsigned short us_sh[1024];   // bf16 Us
  __shared__ float cpart[8][8][72];        // [wave][rb*4+reg][lane] partials
  __shared__ float gpart[8][16];           // [wave][batch] gate partials

  // ---- one-time: Us -> bf16 LDS ----
  if (tid < 256) {
    const float4 uv = *(const float4*)(Us_w + tid*4);
    us_sh[tid*4+0] = f2bf(uv.x); us_sh[tid*4+1] = f2bf(uv.y);
    us_sh[tid*4+2] = f2bf(uv.z); us_sh[tid*4+3] = f2bf(uv.w);
  }

  // ---- A-fragments in registers (bf16), held all 512 steps ----
  // A layout (m89): row = l&15, k = ktile + (l>>4)*8 + j
  bf16x8 whf[2][4];  // [rowblock][kchunk]: rows r_base+rb*16+bm, k=w*128+m*32+lg*8
  bf16x8 wxf[2];     // [rowblock]: x K-chunk k=w*32+lg*8
  float4 wsf0, wsf1; // Ws f32 slice (k=w*32+lg*8, 8 elems) for gate-x
  {
    #pragma unroll
    for (int rb = 0; rb < 2; ++rb) {
      const int ar = r_base + rb*16 + bm;
      #pragma unroll
      for (int m = 0; m < 4; ++m) {
        const int k0 = w*128 + m*32 + lg*8;
        const float4 f0 = *(const float4*)(Wh_w + (size_t)ar*NH + k0);
        const float4 f1 = *(const float4*)(Wh_w + (size_t)ar*NH + k0 + 4);
        whf[rb][m] = pack8(f0, f1);
      }
      const int kx = w*32 + lg*8;
      const float4 g0 = *(const float4*)(Wx_w + (size_t)ar*ND + kx);
      const float4 g1 = *(const float4*)(Wx_w + (size_t)ar*ND + kx + 4);
      wxf[rb] = pack8(g0, g1);
    }
    const int kx = w*32 + lg*8;
    wsf0 = *(const float4*)(Ws_w + kx);
    wsf1 = *(const float4*)(Ws_w + kx + 4);
  }
  const float wxb_r = Wx_b[rg];
  const float whd_r = Wh_w[(size_t)rg*NH + rg];
  const float usr_r = Us_w[rg];
  const float wsb   = Ws_b[0];

  float* const hs_o = out + (size_t)NB*NT;
  float* const g_o  = hs_o + (size_t)NB*NT*NH;
  float* const l_o  = g_o  + (size_t)NB*NT*NH;
  float* const rd_o = l_o  + (size_t)NB*NT*NH;

  __syncthreads();

  float myh = 0.f;           // h_{t-1} for (rg, b_glob); also deferred h out
  float p_sg = 0.f, p_htld = 0.f, p_hp = 0.f;

  for (int t = 0; t < NT; ++t) {
    // ---- x-part: direct f32 loads (K=32 slice), 2 mfma + gate-x ----
    f32x4 acc0 = {0.f, 0.f, 0.f, 0.f};
    f32x4 acc1 = {0.f, 0.f, 0.f, 0.f};
    float ga = 0.f;
    {
      const float* xrow = x + ((size_t)(b_base+bm)*NT + t)*ND + w*32 + lg*8;
      const float4 f0 = *(const float4*)(xrow);
      const float4 f1 = *(const float4*)(xrow + 4);
      const bf16x8 xb = pack8(f0, f1);
      acc0 = __builtin_amdgcn_mfma_f32_16x16x32_bf16(wxf[0], xb, acc0, 0, 0, 0);
      acc1 = __builtin_amdgcn_mfma_f32_16x16x32_bf16(wxf[1], xb, acc1, 0, 0, 0);
      ga += wsf0.x*f0.x + wsf0.y*f0.y + wsf0.z*f0.z + wsf0.w*f0.w
          + wsf1.x*f1.x + wsf1.y*f1.y + wsf1.z*f1.z + wsf1.w*f1.w;
    }

    // ---- wait for h_{t-1} (poll 32 flags), data loads, h mfma ----
    if (t > 0) {
      {
        const unsigned int* fp = flags + ((size_t)bg*NT + (t-1))*32 + (l & 31);
        while (true) {
          unsigned int v;
          asm volatile("global_load_dword %0, %1, off sc0 sc1\n\t"
                       "s_waitcnt vmcnt(0)"
                       : "=v"(v) : "v"(fp) : "memory");
          if (__all((int)(v != 0u))) break;
          __builtin_amdgcn_s_sleep(1);
        }
      }
      __builtin_amdgcn_sched_barrier(0);
      // ---- data loads: 4 x dwordx4 (K=128 slice of batch bm) ----
      const unsigned short* hrow =
          hbuf + ((size_t)((t-1)&1)*NB + b_base + bm)*NH + w*128 + lg*8;
      uint4 hv[4];
      #pragma unroll
      for (int m = 0; m < 4; ++m)
        asm volatile("global_load_dwordx4 %0, %1, off sc0 sc1"
                     : "=v"(hv[m]) : "v"(hrow + m*32) : "memory");
      // ---- deferred outputs of step t-1 (after data4; drain at tail) ----
      {
        const size_t obase = ((size_t)b_glob*NT + (t-1))*NH + rg;
        const float sp  = p_sg * (1.f - p_sg);
        const float rdv = (p_htld - p_hp)*(sp*usr_r) +
                          p_sg*(1.f - p_htld*p_htld)*whd_r;
        const float lv  = 1.f - p_sg;
        asm volatile("global_store_dword %0, %1, off nt"
                     :: "v"(hs_o + obase), "v"(myh) : "memory");
        asm volatile("global_store_dword %0, %1, off nt"
                     :: "v"(g_o + obase), "v"(p_sg) : "memory");
        asm volatile("global_store_dword %0, %1, off nt"
                     :: "v"(l_o + obase), "v"(lv) : "memory");
        asm volatile("global_store_dword %0, %1, off nt"
                     :: "v"(rd_o + obase), "v"(rdv) : "memory");
      }
      // ---- counted wait: data4 retired, outs4 still in flight ----
      asm volatile("s_waitcnt vmcnt(4)" ::: "memory");
      __builtin_amdgcn_sched_barrier(0);
      // ---- h-part: 8 mfma + gate-h ----
      #pragma unroll
      for (int m = 0; m < 4; ++m) {
        const bf16x8 hb = __builtin_bit_cast(bf16x8, hv[m]);
        acc0 = __builtin_amdgcn_mfma_f32_16x16x32_bf16(whf[0][m], hb, acc0, 0, 0, 0);
        acc1 = __builtin_amdgcn_mfma_f32_16x16x32_bf16(whf[1][m], hb, acc1, 0, 0, 0);
        const uint4 uu = *(const uint4*)&us_sh[w*128 + m*32 + lg*8];
        ga += bflo(uu.x)*bflo(hv[m].x) + bfhi(uu.x)*bfhi(hv[m].x)
            + bflo(uu.y)*bflo(hv[m].y) + bfhi(uu.y)*bfhi(hv[m].y)
            + bflo(uu.z)*bflo(hv[m].z) + bfhi(uu.z)*bfhi(hv[m].z)
            + bflo(uu.w)*bflo(hv[m].w) + bfhi(uu.w)*bfhi(hv[m].w);
      }
    }

    // ---- combine partials ----
    ga += __shfl_xor(ga, 16, 64);
    ga += __shfl_xor(ga, 32, 64);
    if (l < 16) gpart[w][l] = ga;
    #pragma unroll
    for (int r = 0; r < 4; ++r) {
      cpart[w][r][l]     = acc0[r];
      cpart[w][4 + r][l] = acc1[r];
    }
    __syncthreads();                   // barrier (a)

    // ---- epilogue: 1 output per thread (row ro 0..31, batch bo 0..15) ----
    // C mapping (m89): col=lane&15 (batch), row=(lane>>4)*4+reg
    float gsum = 0.f, pre0 = 0.f;
    {
      const int rb = ro >> 4, rr = ro & 15;
      const int slot = rb*4 + (rr & 3);
      const int cl   = ((rr >> 2) << 4) | bo;
      #pragma unroll
      for (int ww = 0; ww < 8; ++ww) {
        gsum += gpart[ww][bo];
        pre0 += cpart[ww][slot][cl];
      }
    }
    const float sg   = 1.f / (1.f + expf(-(gsum + wsb)));
    const float pre  = pre0 + wxb_r;
    const float htld = tanhf(pre);
    const float hp   = myh;
    const float h    = (1.f - sg)*hp + sg*htld;
    myh = h; p_sg = sg; p_htld = htld; p_hp = hp;
    {
      const unsigned hb = (unsigned)f2bf(h);
      unsigned short* hptr = hbuf + ((size_t)(t & 1)*NB + b_glob)*NH + rg;
      asm volatile("global_store_short %0, %1, off sc0 sc1"
                   :: "v"(hptr), "v"(hb) : "memory");
    }
    asm volatile("s_waitcnt vmcnt(0)" ::: "memory");
    __syncthreads();                   // barrier (b): all h stores at LLC
    if (tid == 0) {
      unsigned int one = 1u;
      unsigned int* fp = flags + ((size_t)bg*NT + t)*32 + sl;
      asm volatile("global_store_dword %0, %1, off sc0 sc1"
                   :: "v"(fp), "v"(one) : "memory");
    }
  }

  // ---- final step's deferred outputs ----
  {
    const size_t obase = ((size_t)b_glob*NT + (NT-1))*NH + rg;
    const float sp  = p_sg * (1.f - p_sg);
    const float rdv = (p_htld - p_hp)*(sp*usr_r) +
                      p_sg*(1.f - p_htld*p_htld)*whd_r;
    __builtin_nontemporal_store(myh, &hs_o[obase]);
    __builtin_nontemporal_store(p_sg, &g_o[obase]);
    __builtin_nontemporal_store(1.f - p_sg, &l_o[obase]);
    __builtin_nontemporal_store(rdv, &rd_o[obase]);
  }
}

// ys[b,t] = out_w . hs[b,t,:] + out_b
__global__ void yfinish_kernel(const float* __restrict__ hs,
                               const float* __restrict__ out_w,
                               const float* __restrict__ out_b,
                               float* __restrict__ ys)
{
  const int row  = (int)blockIdx.x*4 + ((int)threadIdx.x >> 6);
  const int lane = (int)threadIdx.x & 63;
  const float4* hp = (const float4*)(hs + (size_t)row*NH);
  const float4* wp = (const float4*)out_w;
  float s = 0.f;
  #pragma unroll
  for (int i = 0; i < 4; ++i) {
    const float4 h4 = hp[i*64 + lane];
    const float4 w4 = wp[i*64 + lane];
    s += h4.x*w4.x + h4.y*w4.y + h4.z*w4.z + h4.w*w4.w;
  }
  #pragma unroll
  for (int off = 32; off > 0; off >>= 1) s += __shfl_xor(s, off, 64);
  if (lane == 0) ys[row] = s + out_b[0];
}

extern "C" void kernel_launch(void* const* d_in, const int* in_sizes, int n_in,
                              void* d_out, int out_size, void* d_ws, size_t ws_size,
                              hipStream_t stream)
{
  (void)in_sizes; (void)n_in; (void)out_size; (void)ws_size;
  const float* x     = (const float*)d_in[0];
  const float* Wx_w  = (const float*)d_in[1];
  const float* Wx_b  = (const float*)d_in[2];
  const float* Wh_w  = (const float*)d_in[3];
  const float* Ws_w  = (const float*)d_in[4];
  const float* Ws_b  = (const float*)d_in[5];
  const float* Us_w  = (const float*)d_in[6];
  const float* out_w = (const float*)d_in[7];
  const float* out_b = (const float*)d_in[8];
  float* out = (float*)d_out;

  char* ws = (char*)d_ws;
  unsigned short* hbuf = (unsigned short*)ws;                 // bf16, 256 KB
  unsigned int* flags  = (unsigned int*)(ws + 262144);        // 4*512*32*4 = 256 KB

  hipMemsetAsync(flags, 0, (size_t)4*NT*32*sizeof(unsigned int), stream);
  rnn_step_kernel<<<dim3(128), dim3(512), 0, stream>>>(
      x, Wx_w, Wx_b, Wh_w, Ws_w, Ws_b, Us_w, out, hbuf, flags);
  yfinish_kernel<<<dim3((NB*NT)/4), dim3(256), 0, stream>>>(
      out + (size_t)NB*NT, out_w, out_b, out);
}